// Round 2
// baseline (305.466 us; speedup 1.0000x reference)
//
#include <hip/hip_runtime.h>
#include <math.h>

#define B_TOTAL 8192
#define NN      82
#define HH      10
#define OUTC    5
#define TSTEP   3
#define GRP     3            // thread groups of 82 per block
#define BPT     2            // batch elements per thread
#define BPB     (GRP * BPT)  // 6 batch elements per block
#define THREADS 256
#define ROWP    12           // padded LDS row stride (floats), 48B -> float4 aligned

__device__ __forceinline__ float sigmoid_(float x) {
    return 1.0f / (1.0f + __expf(-x));
}
__device__ __forceinline__ float tanh_(float x) {
    float e = __expf(2.0f * x);
    return 1.0f - 2.0f / (e + 1.0f);
}

// adjI[j*NN + i] = {in_adj[i][j], out_adj[i][j]} : one coalesced dwordx2 per j
// in the main loop (lane = i -> consecutive 8B addresses).
__global__ void transpose_adj_kernel(const float* __restrict__ in_adj,
                                     const float* __restrict__ out_adj,
                                     float2* __restrict__ adjI) {
    int idx = blockIdx.x * blockDim.x + threadIdx.x;
    if (idx < NN * NN) {
        int i = idx / NN;
        int j = idx - i * NN;
        adjI[j * NN + i] = make_float2(in_adj[idx], out_adj[idx]);
    }
}

// one GRU cell update for one (batch,node): fn <- new state, given aggregates
__device__ __forceinline__ void gru_update(
    float fn[HH], const float ai[HH], const float ao[HH],
    const float* __restrict__ w3w, const float* __restrict__ b3w,
    const float* __restrict__ w3u, const float* __restrict__ b3u,
    const float* __restrict__ w4w, const float* __restrict__ b4w,
    const float* __restrict__ w5w, const float* __restrict__ b5w,
    const float* __restrict__ w5u, const float* __restrict__ b5u)
{
    float u3[HH];
    #pragma unroll
    for (int h = 0; h < HH; ++h) {
        float s = b3u[h];
        #pragma unroll
        for (int k = 0; k < HH; ++k) s = fmaf(w3u[h * HH + k], fn[k], s);
        u3[h] = s;
    }

    float zv[HH], rv[HH];
    #pragma unroll
    for (int h = 0; h < HH; ++h) {
        float s1 = b3w[h];
        float s2 = b4w[h];
        #pragma unroll
        for (int k = 0; k < HH; ++k) {
            s1 = fmaf(w3w[h * 2 * HH + k],      ai[k], s1);
            s1 = fmaf(w3w[h * 2 * HH + HH + k], ao[k], s1);
            s2 = fmaf(w4w[h * 2 * HH + k],      ai[k], s2);
            s2 = fmaf(w4w[h * 2 * HH + HH + k], ao[k], s2);
        }
        zv[h] = sigmoid_(s1 + u3[h]);   // reference bug: rv reuses u3 (w3u term)
        rv[h] = sigmoid_(s2 + u3[h]);
    }

    float rf[HH];
    #pragma unroll
    for (int k = 0; k < HH; ++k) rf[k] = rv[k] * fn[k];

    #pragma unroll
    for (int h = 0; h < HH; ++h) {
        float s = b5w[h] + b5u[h];
        #pragma unroll
        for (int k = 0; k < HH; ++k) {
            s = fmaf(w5w[h * 2 * HH + k],      ai[k], s);
            s = fmaf(w5w[h * 2 * HH + HH + k], ao[k], s);
            s = fmaf(w5u[h * HH + k],          rf[k], s);
        }
        float hv = tanh_(s);
        fn[h] = fn[h] + zv[h] * (hv - fn[h]);
    }
}

extern "C" __global__ __launch_bounds__(THREADS)
void ggnn_kernel(const float* __restrict__ x,
                 const float2* __restrict__ adjI,
                 const float* __restrict__ w3w, const float* __restrict__ b3w,
                 const float* __restrict__ w3u, const float* __restrict__ b3u,
                 const float* __restrict__ w4w, const float* __restrict__ b4w,
                 const float* __restrict__ w5w, const float* __restrict__ b5w,
                 const float* __restrict__ w5u, const float* __restrict__ b5u,
                 const float* __restrict__ wout, const float* __restrict__ bout,
                 float* __restrict__ out0, float* __restrict__ out_fn)
{
    __shared__ __align__(16) float nodes[BPB][NN][ROWP];   // 23.6 KB

    const int t     = threadIdx.x;
    const int bbase = blockIdx.x * BPB;
    const int bl    = t / NN;            // group 0..2
    const int node  = t - bl * NN;       // node 0..81
    const bool grp_ok = (bl < GRP);
    const int b0 = bbase + bl;           // slot A batch element (plane bl)
    const int b1 = bbase + bl + GRP;     // slot B batch element (plane bl+GRP)
    const bool a0 = grp_ok && (b0 < B_TOTAL);
    const bool a1 = grp_ok && (b1 < B_TOTAL);

    // ---- cooperative, coalesced load of this block's node states into LDS ----
    {
        const size_t gbase = (size_t)bbase * NN * HH;
        const int    limit = (int)min((size_t)(BPB * NN * HH), (size_t)B_TOTAL * NN * HH - gbase);
        const float* src = x + gbase;
        float* dst = &nodes[0][0][0];
        for (int k = t; k < limit; k += THREADS) {
            int row = k / HH;
            int col = k - row * HH;
            dst[row * ROWP + col] = src[k];
        }
    }
    __syncthreads();

    float fn0[HH], fn1[HH];
    if (grp_ok) {
        #pragma unroll
        for (int h = 0; h < HH; ++h) {
            fn0[h] = nodes[bl][node][h];
            fn1[h] = nodes[bl + GRP][node][h];
        }
    }

    for (int step = 0; step < TSTEP; ++step) {
        float ai0[HH], ao0[HH], ai1[HH], ao1[HH];
        if (grp_ok) {
            #pragma unroll
            for (int h = 0; h < HH; ++h) {
                ai0[h] = 0.0f; ao0[h] = 0.0f; ai1[h] = 0.0f; ao1[h] = 0.0f;
            }

            const float* n0 = &nodes[bl][0][0];
            const float* n1 = &nodes[bl + GRP][0][0];
            const float2* arow = adjI + node;

            #pragma unroll 2
            for (int j = 0; j < NN; ++j) {
                float2 w = arow[j * NN];               // {in, out}, coalesced dwordx2
                const float4* p0 = reinterpret_cast<const float4*>(n0 + j * ROWP);
                const float4* p1 = reinterpret_cast<const float4*>(n1 + j * ROWP);
                float4 v00 = p0[0], v01 = p0[1];
                float2 v02 = *reinterpret_cast<const float2*>(n0 + j * ROWP + 8);
                float4 v10 = p1[0], v11 = p1[1];
                float2 v12 = *reinterpret_cast<const float2*>(n1 + j * ROWP + 8);
                float v0[HH] = {v00.x, v00.y, v00.z, v00.w, v01.x, v01.y, v01.z, v01.w, v02.x, v02.y};
                float v1[HH] = {v10.x, v10.y, v10.z, v10.w, v11.x, v11.y, v11.z, v11.w, v12.x, v12.y};
                #pragma unroll
                for (int h = 0; h < HH; ++h) {
                    ai0[h] = fmaf(w.x, v0[h], ai0[h]);
                    ao0[h] = fmaf(w.y, v0[h], ao0[h]);
                    ai1[h] = fmaf(w.x, v1[h], ai1[h]);
                    ao1[h] = fmaf(w.y, v1[h], ao1[h]);
                }
            }

            gru_update(fn0, ai0, ao0, w3w, b3w, w3u, b3u, w4w, b4w, w5w, b5w, w5u, b5u);
            gru_update(fn1, ai1, ao1, w3w, b3w, w3u, b3u, w4w, b4w, w5w, b5w, w5u, b5u);
        }

        __syncthreads();   // all LDS reads of this step done
        if (grp_ok) {
            #pragma unroll
            for (int h = 0; h < HH; ++h) {
                nodes[bl][node][h]       = fn0[h];
                nodes[bl + GRP][node][h] = fn1[h];
            }
        }
        __syncthreads();   // updated states visible for next step
    }

    // ---- output layer: tanh(concat(fn, x) @ wout^T + bout), plus fn itself ----
    #pragma unroll
    for (int s = 0; s < BPT; ++s) {
        const bool act = (s == 0) ? a0 : a1;
        if (!act) continue;
        const int b = (s == 0) ? b0 : b1;
        const float* fn = (s == 0) ? fn0 : fn1;

        size_t row = (size_t)b * NN + node;
        const float* xr = x + row * HH;
        float xi[HH];
        #pragma unroll
        for (int h = 0; h < HH; ++h) xi[h] = xr[h];

        #pragma unroll
        for (int c = 0; c < OUTC; ++c) {
            float s2 = bout[c];
            #pragma unroll
            for (int k = 0; k < HH; ++k) s2 = fmaf(wout[c * 2 * HH + k],      fn[k], s2);
            #pragma unroll
            for (int k = 0; k < HH; ++k) s2 = fmaf(wout[c * 2 * HH + HH + k], xi[k], s2);
            out0[row * OUTC + c] = tanh_(s2);
        }
        #pragma unroll
        for (int h = 0; h < HH; ++h) out_fn[row * HH + h] = fn[h];
    }
}

extern "C" void kernel_launch(void* const* d_in, const int* in_sizes, int n_in,
                              void* d_out, int out_size, void* d_ws, size_t ws_size,
                              hipStream_t stream) {
    const float* x       = (const float*)d_in[0];
    const float* in_adj  = (const float*)d_in[1];
    const float* out_adj = (const float*)d_in[2];
    const float* w3w = (const float*)d_in[3];
    const float* b3w = (const float*)d_in[4];
    const float* w3u = (const float*)d_in[5];
    const float* b3u = (const float*)d_in[6];
    const float* w4w = (const float*)d_in[7];
    const float* b4w = (const float*)d_in[8];
    const float* w5w = (const float*)d_in[9];
    const float* b5w = (const float*)d_in[10];
    const float* w5u = (const float*)d_in[11];
    const float* b5u = (const float*)d_in[12];
    const float* wout = (const float*)d_in[13];
    const float* bout = (const float*)d_in[14];

    float2* adjI = (float2*)d_ws;                    // 82*82 float2 = 53.8 KB
    float* out0 = (float*)d_out;
    float* out_fn = out0 + (size_t)B_TOTAL * NN * OUTC;

    transpose_adj_kernel<<<(NN * NN + 255) / 256, 256, 0, stream>>>(in_adj, out_adj, adjI);

    int grid = (B_TOTAL + BPB - 1) / BPB;            // 1366
    ggnn_kernel<<<grid, THREADS, 0, stream>>>(
        x, adjI, w3w, b3w, w3u, b3u, w4w, b4w, w5w, b5w, w5u, b5u,
        wout, bout, out0, out_fn);
}